// Round 1
// baseline (534.160 us; speedup 1.0000x reference)
//
#include <hip/hip_runtime.h>

// ---------------------------------------------------------------------------
// VoxelTripletLoss on MI355X — Round 1: correct f32 implementation.
// B=64 anchors, M=2048 memory slots, FEAT=512, N=32^3=32768 voxels.
//
// Pipeline:
//   K1 prep:      v_sq[b], 1/||anchor_b||, 1/||key_m||
//   K2 gemm_nt:   dot_part[ns][b][m] (+= V·W^T over n-split), wsq_part[ns][m]
//   K3 gemm_nt:   key_dot[b][m] = anchor·keys^T (same kernel, K=512)
//   K4 rowreduce: per-b hardest_pos/neg under sv-mask -> loss[b], valid[b]
//   K5 final:     masked mean -> d_out[0]
// ---------------------------------------------------------------------------

constexpr int   Bdim  = 64;
constexpr int   Mdim  = 2048;
constexpr int   FEATC = 512;
constexpr int   Nvox  = 32768;
constexpr int   NSPLIT = 32;          // N-splits for the big GEMM (grid depth)
constexpr int   CH    = 64;           // n-chunk staged per iteration
constexpr int   LSTR  = 68;           // LDS row stride (floats), pad 64->68
constexpr float BETA   = 0.8333333f;
constexpr float MARGIN = 0.2f;
constexpr float BIGV   = 1.0e9f;

// workspace layout, in float offsets
constexpr size_t OFF_VSQ   = 0;                          // 64
constexpr size_t OFF_AINV  = 64;                         // 64
constexpr size_t OFF_KINV  = 128;                        // 2048
constexpr size_t OFF_WSQP  = 2176;                       // NSPLIT*2048
constexpr size_t OFF_LOSS  = OFF_WSQP + (size_t)NSPLIT * Mdim;   // 64
constexpr size_t OFF_VALID = OFF_LOSS + 64;              // 64
constexpr size_t OFF_DOTP  = OFF_VALID + 64;             // NSPLIT*64*2048
constexpr size_t OFF_KEYP  = OFF_DOTP + (size_t)NSPLIT * Bdim * Mdim; // 64*2048

// ---------------------------------------------------------------------------
// K1: row norms / sums of squares
// blocks [0,64): v_sq over 32768 voxels; blocks [64,592): 4 feature rows each
// ---------------------------------------------------------------------------
__global__ __launch_bounds__(256) void prep_kernel(
    const float* __restrict__ vox, const float* __restrict__ anc,
    const float* __restrict__ keys,
    float* __restrict__ vsq, float* __restrict__ ainv, float* __restrict__ kinv)
{
    const int tid = threadIdx.x;
    __shared__ float sb[4];
    if (blockIdx.x < 64) {
        const int b = blockIdx.x;
        const float4* src = reinterpret_cast<const float4*>(vox + (size_t)b * Nvox);
        float p = 0.f;
        for (int i = tid; i < Nvox / 4; i += 256) {
            float4 x = src[i];
            p = fmaf(x.x, x.x, p); p = fmaf(x.y, x.y, p);
            p = fmaf(x.z, x.z, p); p = fmaf(x.w, x.w, p);
        }
        #pragma unroll
        for (int off = 32; off > 0; off >>= 1) p += __shfl_down(p, off);
        if ((tid & 63) == 0) sb[tid >> 6] = p;
        __syncthreads();
        if (tid == 0) vsq[b] = sb[0] + sb[1] + sb[2] + sb[3];
    } else {
        const int r = (blockIdx.x - 64) * 4 + (tid >> 6);   // 0..2111
        const int lane = tid & 63;
        const float* src = (r < 64) ? (anc + (size_t)r * FEATC)
                                    : (keys + (size_t)(r - 64) * FEATC);
        const float4* s4 = reinterpret_cast<const float4*>(src);
        float4 x = s4[lane];
        float4 y = s4[lane + 64];
        float p = 0.f;
        p = fmaf(x.x, x.x, p); p = fmaf(x.y, x.y, p);
        p = fmaf(x.z, x.z, p); p = fmaf(x.w, x.w, p);
        p = fmaf(y.x, y.x, p); p = fmaf(y.y, y.y, p);
        p = fmaf(y.z, y.z, p); p = fmaf(y.w, y.w, p);
        #pragma unroll
        for (int off = 32; off > 0; off >>= 1) p += __shfl_down(p, off);
        if (lane == 0) {
            float inv = 1.f / fmaxf(sqrtf(p), 1e-8f);
            if (r < 64) ainv[r] = inv; else kinv[r - 64] = inv;
        }
    }
}

// ---------------------------------------------------------------------------
// K2/K3: C[64 x 2048] += V[64 x K] * W[2048 x K]^T over one n-split.
// Block tile: all 64 b-rows x 64 m-rows; 256 threads = 4 c-slices x (8bg x 8mg);
// per-thread register tile 8x8 with STRIDED row assignment (b = bg+8i,
// m = mg+8j) so ds_read_b128 fragment loads are bank-conflict-free
// (bank = 4*bg + c, all 32 banks covered; mg-lanes broadcast).
// wsq (optional) accumulated during W staging (each thread stages one row).
// ---------------------------------------------------------------------------
__global__ __launch_bounds__(256) void gemm_nt(
    const float* __restrict__ V, const float* __restrict__ W,
    float* __restrict__ dotp, float* __restrict__ wsqp,
    int K, int n_per_split, int m_blocks)
{
    __shared__ float v_lds[64 * LSTR];
    __shared__ float w_lds[64 * LSTR];
    __shared__ float redbuf[4096];

    const int tid   = threadIdx.x;
    const int bg    = tid & 7;
    const int mg    = (tid >> 3) & 7;
    const int slice = tid >> 6;                 // 0..3 (== wave id)
    const int mb    = blockIdx.x % m_blocks;
    const int ns    = blockIdx.x / m_blocks;
    const int srow  = tid >> 2;                 // staging row 0..63
    const int sc    = (tid & 3) * 4;            // staging col base

    const float* vrow = V + (size_t)srow * K;
    const float* wrow = W + (size_t)(mb * 64 + srow) * K;

    float acc[8][8];
    #pragma unroll
    for (int i = 0; i < 8; ++i)
        #pragma unroll
        for (int j = 0; j < 8; ++j) acc[i][j] = 0.f;
    float wsq = 0.f;

    const int n0base = ns * n_per_split;
    const int chunks = n_per_split / CH;

    for (int ch = 0; ch < chunks; ++ch) {
        const int n0 = n0base + ch * CH;
        float4 va[4], wa[4];
        #pragma unroll
        for (int k = 0; k < 4; ++k) {
            va[k] = *reinterpret_cast<const float4*>(vrow + n0 + sc + 16 * k);
            wa[k] = *reinterpret_cast<const float4*>(wrow + n0 + sc + 16 * k);
        }
        __syncthreads();    // previous compute phase done before overwrite
        #pragma unroll
        for (int k = 0; k < 4; ++k) {
            *reinterpret_cast<float4*>(&v_lds[srow * LSTR + sc + 16 * k]) = va[k];
            *reinterpret_cast<float4*>(&w_lds[srow * LSTR + sc + 16 * k]) = wa[k];
            wsq = fmaf(wa[k].x, wa[k].x, wsq);
            wsq = fmaf(wa[k].y, wa[k].y, wsq);
            wsq = fmaf(wa[k].z, wa[k].z, wsq);
            wsq = fmaf(wa[k].w, wa[k].w, wsq);
        }
        __syncthreads();
        #pragma unroll
        for (int st = 0; st < 4; ++st) {
            const int c = slice * 16 + st * 4;
            float4 ww[8];
            #pragma unroll
            for (int j = 0; j < 8; ++j)
                ww[j] = *reinterpret_cast<const float4*>(&w_lds[(mg + 8 * j) * LSTR + c]);
            #pragma unroll
            for (int i = 0; i < 8; ++i) {
                const float4 vv = *reinterpret_cast<const float4*>(&v_lds[(bg + 8 * i) * LSTR + c]);
                #pragma unroll
                for (int j = 0; j < 8; ++j) {
                    float a = acc[i][j];
                    a = fmaf(vv.x, ww[j].x, a);
                    a = fmaf(vv.y, ww[j].y, a);
                    a = fmaf(vv.z, ww[j].z, a);
                    a = fmaf(vv.w, ww[j].w, a);
                    acc[i][j] = a;
                }
            }
        }
    }

    // cross-slice (4-way) combine in LDS, deterministic order
    __syncthreads();
    for (int s = 0; s < 4; ++s) {
        if (slice == s) {
            #pragma unroll
            for (int i = 0; i < 8; ++i)
                #pragma unroll
                for (int j = 0; j < 8; ++j) {
                    const int idx = (bg + 8 * i) * 64 + (mg + 8 * j);
                    if (s == 0) redbuf[idx] = acc[i][j];
                    else        redbuf[idx] += acc[i][j];
                }
        }
        __syncthreads();
    }
    for (int k2 = tid; k2 < 4096; k2 += 256) {
        const int bt = k2 >> 6, mt = k2 & 63;
        dotp[((size_t)ns * 64 + bt) * Mdim + mb * 64 + mt] = redbuf[k2];
    }
    if (wsqp) {
        __syncthreads();               // done reading redbuf above
        redbuf[tid] = wsq;             // tid = srow*4 + sub
        __syncthreads();
        if (tid < 64) {
            float s = redbuf[tid * 4] + redbuf[tid * 4 + 1]
                    + redbuf[tid * 4 + 2] + redbuf[tid * 4 + 3];
            wsqp[(size_t)ns * Mdim + mb * 64 + tid] = s;
        }
    }
}

// ---------------------------------------------------------------------------
// K4: per-anchor hardest positive/negative under the sv mask
// ---------------------------------------------------------------------------
__global__ __launch_bounds__(256) void rowreduce_kernel(
    const float* __restrict__ dotp, const float* __restrict__ wsqp,
    const float* __restrict__ keyp, const float* __restrict__ vsq,
    const float* __restrict__ ainv, const float* __restrict__ kinv,
    float* __restrict__ lossb, float* __restrict__ validb)
{
    const int b = blockIdx.x;
    const int tid = threadIdx.x;
    const float vs = vsq[b];
    const float ai = ainv[b];
    float hp = -BIGV, hn = BIGV, ap = 0.f, an = 0.f;
    for (int m = tid; m < Mdim; m += 256) {
        float dot = 0.f;
        #pragma unroll
        for (int s = 0; s < NSPLIT; ++s)
            dot += dotp[((size_t)s * 64 + b) * Mdim + m];
        float wq = 0.f;
        #pragma unroll
        for (int s = 0; s < NSPLIT; ++s)
            wq += wsqp[(size_t)s * Mdim + m];
        const float sv = 1.f - (vs + wq - 2.f * dot) * (1.f / 32768.f);
        const float kd = 1.f - keyp[(size_t)b * Mdim + m] * ai * kinv[m];
        if (sv > BETA) { ap = 1.f; hp = fmaxf(hp, kd); }
        if (sv < BETA) { an = 1.f; hn = fminf(hn, kd); }
    }
    #pragma unroll
    for (int off = 32; off > 0; off >>= 1) {
        hp = fmaxf(hp, __shfl_down(hp, off));
        hn = fminf(hn, __shfl_down(hn, off));
        ap = fmaxf(ap, __shfl_down(ap, off));
        an = fmaxf(an, __shfl_down(an, off));
    }
    __shared__ float sb[16];
    const int wv = tid >> 6;
    if ((tid & 63) == 0) {
        sb[wv * 4 + 0] = hp; sb[wv * 4 + 1] = hn;
        sb[wv * 4 + 2] = ap; sb[wv * 4 + 3] = an;
    }
    __syncthreads();
    if (tid == 0) {
        for (int w2 = 1; w2 < 4; ++w2) {
            hp = fmaxf(hp, sb[w2 * 4 + 0]);
            hn = fminf(hn, sb[w2 * 4 + 1]);
            ap = fmaxf(ap, sb[w2 * 4 + 2]);
            an = fmaxf(an, sb[w2 * 4 + 3]);
        }
        lossb[b]  = fmaxf(hp - hn + MARGIN, 0.f);
        validb[b] = (ap > 0.f && an > 0.f) ? 1.f : 0.f;
    }
}

// ---------------------------------------------------------------------------
// K5: masked mean over 64 anchors -> scalar
// ---------------------------------------------------------------------------
__global__ void final_kernel(const float* __restrict__ lossb,
                             const float* __restrict__ validb,
                             float* __restrict__ out)
{
    const int t = threadIdx.x;   // 64 threads = 1 wave
    float l = lossb[t] * validb[t];
    float c = validb[t];
    #pragma unroll
    for (int off = 32; off > 0; off >>= 1) {
        l += __shfl_down(l, off);
        c += __shfl_down(c, off);
    }
    if (t == 0) out[0] = (c > 0.f) ? (l / c) : 0.f;
}

// ---------------------------------------------------------------------------
extern "C" void kernel_launch(void* const* d_in, const int* in_sizes, int n_in,
                              void* d_out, int out_size, void* d_ws, size_t ws_size,
                              hipStream_t stream) {
    const float* anchor = (const float*)d_in[0];   // (64, 512)
    const float* voxels = (const float*)d_in[1];   // (64, 32768)
    const float* keys   = (const float*)d_in[2];   // (2048, 512)
    const float* vals   = (const float*)d_in[3];   // (2048, 32768)

    float* ws     = (float*)d_ws;
    float* vsq    = ws + OFF_VSQ;
    float* ainv   = ws + OFF_AINV;
    float* kinv   = ws + OFF_KINV;
    float* wsqp   = ws + OFF_WSQP;
    float* lossb  = ws + OFF_LOSS;
    float* validb = ws + OFF_VALID;
    float* dotp   = ws + OFF_DOTP;
    float* keyp   = ws + OFF_KEYP;

    prep_kernel<<<592, 256, 0, stream>>>(voxels, anchor, keys, vsq, ainv, kinv);
    // big GEMM: 32 m-blocks x 32 n-splits (1024 blocks, ~3 blocks/CU)
    gemm_nt<<<32 * NSPLIT, 256, 0, stream>>>(voxels, vals, dotp, wsqp,
                                             Nvox, Nvox / NSPLIT, 32);
    // key GEMM: 32 m-blocks, single split (K = 512)
    gemm_nt<<<32, 256, 0, stream>>>(anchor, keys, keyp, nullptr,
                                    FEATC, FEATC, 32);
    rowreduce_kernel<<<64, 256, 0, stream>>>(dotp, wsqp, keyp, vsq, ainv, kinv,
                                             lossb, validb);
    final_kernel<<<1, 64, 0, stream>>>(lossb, validb, (float*)d_out);
}

// Round 2
// 413.279 us; speedup vs baseline: 1.2925x; 1.2925x over previous
//
#include <hip/hip_runtime.h>

// ---------------------------------------------------------------------------
// VoxelTripletLoss — Round 2: MFMA split-bf16 GEMM, memory-bound design.
// B=64, M=2048, FEAT=512, N=32768.
//
//   K1 prep:     V -> (v_hi, v_lo) bf16 in MFMA-frag-permuted layout, v_sq
//                partials, 1/||anchor||, 1/||key||
//   K2 gemm_big: dotp[ns][b][m] via mfma_f32_32x32x16_bf16 (v_hi*w + v_lo*w),
//                wsqp[ns][m] from the f32 W values during staging
//   K3 keydist:  keyp[b][m] = anchor.keys^T (f32, K=512) + wsq reduce
//   K4 rowpart:  per (b, m-slice) hardest pos/neg partials
//   K5 final:    combine partials -> masked mean -> d_out[0]
// ---------------------------------------------------------------------------

typedef __attribute__((ext_vector_type(8)))  short bf16x8;
typedef __attribute__((ext_vector_type(16))) float f32x16;

constexpr int   Mdim   = 2048;
constexpr int   Nvox   = 32768;
constexpr int   NS     = 16;        // k-splits for big GEMM
constexpr float BETA   = 0.8333333f;
constexpr float MARGIN = 0.2f;
constexpr float BIGV   = 1.0e9f;

// workspace layout (float offsets); total 17.46 MB
constexpr size_t OFF_VSQP = 0;                       // 64*16
constexpr size_t OFF_AINV = 1024;                    // 64
constexpr size_t OFF_KINV = 1088;                    // 2048
constexpr size_t OFF_WSQ  = 3136;                    // 2048
constexpr size_t OFF_WSQP = 5184;                    // NS*2048 = 32768
constexpr size_t OFF_PHP  = 37952;                   // 256
constexpr size_t OFF_PHN  = 38208;                   // 256
constexpr size_t OFF_PAP  = 38464;                   // 256
constexpr size_t OFF_PAN  = 38720;                   // 256
constexpr size_t OFF_KEYP = 38976;                   // 64*2048 = 131072
constexpr size_t OFF_DOTP = 170048;                  // NS*64*2048 = 2097152
constexpr size_t OFF_VHI  = 2267200;                 // 2M ushort = 1048576 floats
constexpr size_t OFF_VLO  = 3315776;                 // 1048576 floats

__device__ __forceinline__ unsigned int bf16rne(float x) {
    unsigned int u = __float_as_uint(x);
    return (u + 0x7FFFu + ((u >> 16) & 1u)) >> 16;   // RNE to bf16, returns low 16 bits
}
__device__ __forceinline__ int pk2(unsigned int lo, unsigned int hi) {
    return (int)(lo | (hi << 16));                    // element k in low short
}
__device__ __forceinline__ void async16(const ushort* g, ushort* l) {
    __builtin_amdgcn_global_load_lds(
        (const __attribute__((address_space(1))) unsigned int*)g,
        (__attribute__((address_space(3))) unsigned int*)l, 16, 0, 0);
}

// ---------------------------------------------------------------------------
// K1 prep.
// Blocks [0,256): V convert. 16 b-groups (4 rows) x 16 k-slices (2048 k).
//   frag-perm layout (ushort idx): chunk c=k>>6: c*4096 + (b>>5)*2048
//     + ((k>>4)&3)*512 + ((b&31) + 32*((k>>3)&1))*8 + (k&7)
//   -> GEMM stages chunks with global_load_lds, frag reads are canonical.
// Blocks [256,784): feature-row norms (4 rows per block), as round 1.
// ---------------------------------------------------------------------------
__global__ __launch_bounds__(256) void prep_kernel(
    const float* __restrict__ vox, const float* __restrict__ anc,
    const float* __restrict__ keys,
    ushort* __restrict__ vhi, ushort* __restrict__ vlo,
    float* __restrict__ vsqp, float* __restrict__ ainv, float* __restrict__ kinv)
{
    const int tid = threadIdx.x;
    if (blockIdx.x < 256) {
        const int bg = blockIdx.x >> 4;      // 0..15
        const int ks = blockIdx.x & 15;      // 0..15
        const int bsub = tid & 3;
        const int b  = bg * 4 + bsub;
        const int kw = tid >> 2;             // 0..63
        float sq = 0.f;
        #pragma unroll
        for (int it = 0; it < 2; ++it) {
            const int kloc = ks * 2048 + (it * 64 + kw) * 16;
            const float4* src = reinterpret_cast<const float4*>(vox + (size_t)b * Nvox + kloc);
            float4 x[4];
            #pragma unroll
            for (int j = 0; j < 4; ++j) x[j] = src[j];
            unsigned int h[16], l[16];
            #pragma unroll
            for (int j = 0; j < 4; ++j) {
                const float e[4] = {x[j].x, x[j].y, x[j].z, x[j].w};
                #pragma unroll
                for (int q = 0; q < 4; ++q) {
                    const float v = e[q];
                    sq = fmaf(v, v, sq);
                    const unsigned int hb = bf16rne(v);
                    h[j*4+q] = hb;
                    const float r = v - __uint_as_float(hb << 16);
                    l[j*4+q] = bf16rne(r);
                }
            }
            const int c = kloc >> 6, s = (kloc >> 4) & 3;
            const size_t base = (size_t)c * 4096 + (b >> 5) * 2048 + s * 512 + (b & 31) * 8;
            int4 hp0 = { pk2(h[0],h[1]), pk2(h[2],h[3]), pk2(h[4],h[5]), pk2(h[6],h[7]) };
            int4 hp1 = { pk2(h[8],h[9]), pk2(h[10],h[11]), pk2(h[12],h[13]), pk2(h[14],h[15]) };
            int4 lp0 = { pk2(l[0],l[1]), pk2(l[2],l[3]), pk2(l[4],l[5]), pk2(l[6],l[7]) };
            int4 lp1 = { pk2(l[8],l[9]), pk2(l[10],l[11]), pk2(l[12],l[13]), pk2(l[14],l[15]) };
            *reinterpret_cast<int4*>(vhi + base)       = hp0;
            *reinterpret_cast<int4*>(vhi + base + 256) = hp1;
            *reinterpret_cast<int4*>(vlo + base)       = lp0;
            *reinterpret_cast<int4*>(vlo + base + 256) = lp1;
        }
        // reduce sq per bsub: lanes 0..3 of each wave end with the wave sum
        #pragma unroll
        for (int off = 32; off >= 4; off >>= 1) sq += __shfl_down(sq, off);
        __shared__ float red[16];
        const int lane = tid & 63, wave = tid >> 6;
        if (lane < 4) red[wave * 4 + lane] = sq;
        __syncthreads();
        if (tid < 4)
            vsqp[(size_t)(bg * 4 + tid) * 16 + ks] =
                red[tid] + red[tid + 4] + red[tid + 8] + red[tid + 12];
    } else {
        const int r = (blockIdx.x - 256) * 4 + (tid >> 6);   // 0..2111
        const int lane = tid & 63;
        const float* src = (r < 64) ? (anc + (size_t)r * 512)
                                    : (keys + (size_t)(r - 64) * 512);
        const float4* s4 = reinterpret_cast<const float4*>(src);
        float4 x = s4[lane];
        float4 y = s4[lane + 64];
        float p = 0.f;
        p = fmaf(x.x, x.x, p); p = fmaf(x.y, x.y, p);
        p = fmaf(x.z, x.z, p); p = fmaf(x.w, x.w, p);
        p = fmaf(y.x, y.x, p); p = fmaf(y.y, y.y, p);
        p = fmaf(y.z, y.z, p); p = fmaf(y.w, y.w, p);
        #pragma unroll
        for (int off = 32; off > 0; off >>= 1) p += __shfl_down(p, off);
        if (lane == 0) {
            float inv = 1.f / fmaxf(sqrtf(p), 1e-8f);
            if (r < 64) ainv[r] = inv; else kinv[r - 64] = inv;
        }
    }
}

// ---------------------------------------------------------------------------
// K2: dotp[ns][64][2048] via MFMA. Block = 64 b x 64 m, 4 waves as 2x2 of
// 32x32 tiles. Per 64-k chunk: V hi/lo via global_load_lds (frag order),
// W loaded f32 (register-prefetched), converted to bf16, ds_written in frag
// order. 2 MFMAs per k-step: acc += vhi*w; acc += vlo*w.
// ---------------------------------------------------------------------------
__global__ __launch_bounds__(256) void gemm_big(
    const ushort* __restrict__ vhi, const ushort* __restrict__ vlo,
    const float* __restrict__ W,
    float* __restrict__ dotp, float* __restrict__ wsqp)
{
    __shared__ ushort sVhi[4096], sVlo[4096], sWhi[4096];   // 8 KB each
    __shared__ float red[256];

    const int tid  = threadIdx.x;
    const int lane = tid & 63;
    const int wave = tid >> 6;
    const int mb   = blockIdx.x & 31;       // m-block
    const int ns   = blockIdx.x >> 5;       // k-split
    const int srow = tid >> 2;              // staged W row 0..63
    const int sq   = tid & 3;               // k-step within chunk

    const float*  wptr = W + (size_t)(mb * 64 + srow) * Nvox + ns * 2048 + sq * 16;
    const ushort* vhig = vhi + (size_t)(ns * 32) * 4096 + wave * 1024 + lane * 8;
    const ushort* vlog = vlo + (size_t)(ns * 32) * 4096 + wave * 1024 + lane * 8;
    ushort* ldsVhi = &sVhi[wave * 1024];    // lane-uniform DMA dest
    ushort* ldsVlo = &sVlo[wave * 1024];

    const int wr = wave >> 1, wc = wave & 1;
    f32x16 acc = {};
    float wsq = 0.f;

    float4 wreg[4];
    #pragma unroll
    for (int j = 0; j < 4; ++j) wreg[j] = *reinterpret_cast<const float4*>(wptr + j * 4);

    const int woff0 = (srow >> 5) * 2048 + sq * 512 + (srow & 31) * 8;

    for (int ch = 0; ch < 32; ++ch) {
        // convert W chunk (already in regs), accumulate f32 sum of squares
        int4 p0, p1;
        {
            unsigned int hb[16];
            #pragma unroll
            for (int j = 0; j < 4; ++j) {
                const float e[4] = {wreg[j].x, wreg[j].y, wreg[j].z, wreg[j].w};
                #pragma unroll
                for (int q = 0; q < 4; ++q) {
                    wsq = fmaf(e[q], e[q], wsq);
                    hb[j*4+q] = bf16rne(e[q]);
                }
            }
            p0 = (int4){ pk2(hb[0],hb[1]), pk2(hb[2],hb[3]), pk2(hb[4],hb[5]), pk2(hb[6],hb[7]) };
            p1 = (int4){ pk2(hb[8],hb[9]), pk2(hb[10],hb[11]), pk2(hb[12],hb[13]), pk2(hb[14],hb[15]) };
        }
        __syncthreads();                     // all waves done reading prev chunk
        // async V hi/lo -> LDS (each wave: its 2 KB quarter, 1 KB per instr)
        async16(vhig + (size_t)ch * 4096,       ldsVhi);
        async16(vhig + (size_t)ch * 4096 + 512, ldsVhi + 512);
        async16(vlog + (size_t)ch * 4096,       ldsVlo);
        async16(vlog + (size_t)ch * 4096 + 512, ldsVlo + 512);
        // W bf16 -> LDS frag order
        *reinterpret_cast<int4*>(&sWhi[woff0])       = p0;
        *reinterpret_cast<int4*>(&sWhi[woff0 + 256]) = p1;
        // prefetch next W chunk (drained by barrier2's vmcnt wait)
        if (ch < 31) {
            #pragma unroll
            for (int j = 0; j < 4; ++j)
                wreg[j] = *reinterpret_cast<const float4*>(wptr + (ch + 1) * 64 + j * 4);
        }
        __syncthreads();                     // V DMA + W writes visible
        #pragma unroll
        for (int s = 0; s < 4; ++s) {
            bf16x8 ah = *reinterpret_cast<const bf16x8*>(&sVhi[wr * 2048 + s * 512 + lane * 8]);
            bf16x8 al = *reinterpret_cast<const bf16x8*>(&sVlo[wr * 2048 + s * 512 + lane * 8]);
            bf16x8 bh = *reinterpret_cast<const bf16x8*>(&sWhi[wc * 2048 + s * 512 + lane * 8]);
            acc = __builtin_amdgcn_mfma_f32_32x32x16_bf16(ah, bh, acc, 0, 0, 0);
            acc = __builtin_amdgcn_mfma_f32_32x32x16_bf16(al, bh, acc, 0, 0, 0);
        }
    }

    // epilogue: C layout col=lane&31, row=(reg&3)+8*(reg>>2)+4*(lane>>5)
    const int col   = lane & 31;
    const int rbase = 4 * (lane >> 5);
    const size_t out_m = (size_t)(mb * 64 + wc * 32 + col);
    #pragma unroll
    for (int r = 0; r < 16; ++r) {
        const int row = (r & 3) + 8 * (r >> 2) + rbase;
        const int b   = wr * 32 + row;
        dotp[(size_t)(ns * 64 + b) * Mdim + out_m] = acc[r];
    }
    red[tid] = wsq;
    __syncthreads();
    if (tid < 64)
        wsqp[(size_t)ns * Mdim + mb * 64 + tid] =
            red[tid*4] + red[tid*4+1] + red[tid*4+2] + red[tid*4+3];
}

// ---------------------------------------------------------------------------
// K3: blocks [0,256): key dots (8 m-rows per block, keys staged in LDS);
//     blocks [256,264): wsq[m] = sum_s wsqp[s][m]
// ---------------------------------------------------------------------------
__global__ __launch_bounds__(256) void keydist_kernel(
    const float* __restrict__ anc, const float* __restrict__ keys,
    const float* __restrict__ wsqp, float* __restrict__ keyp,
    float* __restrict__ wsq)
{
    const int tid = threadIdx.x;
    if (blockIdx.x >= 256) {
        const int m = (blockIdx.x - 256) * 256 + tid;
        float s = 0.f;
        #pragma unroll
        for (int sp = 0; sp < NS; ++sp) s += wsqp[(size_t)sp * Mdim + m];
        wsq[m] = s;
        return;
    }
    __shared__ float kk[8 * 516];
    const int mt = blockIdx.x * 8;
    {
        const int row = tid >> 5, colb = (tid & 31) * 16;
        const float4* src = reinterpret_cast<const float4*>(keys + (size_t)(mt + row) * 512 + colb);
        #pragma unroll
        for (int j = 0; j < 4; ++j)
            *reinterpret_cast<float4*>(&kk[row * 516 + colb + j * 4]) = src[j];
    }
    __syncthreads();
    const int b = tid >> 2, msub = tid & 3;
    const float* arow = anc + (size_t)b * 512;
    const float* k0 = &kk[msub * 516];
    const float* k1 = &kk[(msub + 4) * 516];
    float d0 = 0.f, d1 = 0.f;
    for (int k = 0; k < 512; k += 4) {
        const float4 a = *reinterpret_cast<const float4*>(arow + k);
        const float4 x = *reinterpret_cast<const float4*>(k0 + k);
        const float4 y = *reinterpret_cast<const float4*>(k1 + k);
        d0 = fmaf(a.x, x.x, d0); d0 = fmaf(a.y, x.y, d0);
        d0 = fmaf(a.z, x.z, d0); d0 = fmaf(a.w, x.w, d0);
        d1 = fmaf(a.x, y.x, d1); d1 = fmaf(a.y, y.y, d1);
        d1 = fmaf(a.z, y.z, d1); d1 = fmaf(a.w, y.w, d1);
    }
    keyp[(size_t)b * Mdim + mt + msub]     = d0;
    keyp[(size_t)b * Mdim + mt + msub + 4] = d1;
}

// ---------------------------------------------------------------------------
// K4: grid 256 = 64 b x 4 m-slices (512 m each): partial hardest pos/neg
// ---------------------------------------------------------------------------
__global__ __launch_bounds__(256) void rowpart_kernel(
    const float* __restrict__ dotp, const float* __restrict__ wsq,
    const float* __restrict__ keyp, const float* __restrict__ vsqp,
    const float* __restrict__ ainv, const float* __restrict__ kinv,
    float* __restrict__ php, float* __restrict__ phn,
    float* __restrict__ pap, float* __restrict__ pan)
{
    const int bid = blockIdx.x, tid = threadIdx.x;
    const int b = bid >> 2, sl = bid & 3;
    float vs = 0.f;
    #pragma unroll
    for (int i = 0; i < 16; ++i) vs += vsqp[(size_t)b * 16 + i];
    const float ai = ainv[b];
    float hp = -BIGV, hn = BIGV, ap = 0.f, an = 0.f;
    #pragma unroll
    for (int rep = 0; rep < 2; ++rep) {
        const int m = sl * 512 + rep * 256 + tid;
        float dot = 0.f;
        #pragma unroll
        for (int s = 0; s < NS; ++s) dot += dotp[(size_t)(s * 64 + b) * Mdim + m];
        const float sv = 1.f - (vs + wsq[m] - 2.f * dot) * (1.f / 32768.f);
        const float kd = 1.f - keyp[(size_t)b * Mdim + m] * ai * kinv[m];
        if (sv > BETA) { ap = 1.f; hp = fmaxf(hp, kd); }
        if (sv < BETA) { an = 1.f; hn = fminf(hn, kd); }
    }
    #pragma unroll
    for (int off = 32; off > 0; off >>= 1) {
        hp = fmaxf(hp, __shfl_down(hp, off));
        hn = fminf(hn, __shfl_down(hn, off));
        ap = fmaxf(ap, __shfl_down(ap, off));
        an = fmaxf(an, __shfl_down(an, off));
    }
    __shared__ float sb[16];
    const int wv = tid >> 6;
    if ((tid & 63) == 0) {
        sb[wv * 4 + 0] = hp; sb[wv * 4 + 1] = hn;
        sb[wv * 4 + 2] = ap; sb[wv * 4 + 3] = an;
    }
    __syncthreads();
    if (tid == 0) {
        for (int w2 = 1; w2 < 4; ++w2) {
            hp = fmaxf(hp, sb[w2 * 4 + 0]);
            hn = fminf(hn, sb[w2 * 4 + 1]);
            ap = fmaxf(ap, sb[w2 * 4 + 2]);
            an = fmaxf(an, sb[w2 * 4 + 3]);
        }
        php[bid] = hp; phn[bid] = hn; pap[bid] = ap; pan[bid] = an;
    }
}

// ---------------------------------------------------------------------------
// K5: single block: combine 4 partials per b -> loss/valid -> masked mean
// ---------------------------------------------------------------------------
__global__ void final_kernel(const float* __restrict__ php, const float* __restrict__ phn,
                             const float* __restrict__ pap, const float* __restrict__ pan,
                             float* __restrict__ out)
{
    const int t = threadIdx.x;   // 256
    float hp = php[t], hn = phn[t], ap = pap[t], an = pan[t];
    hp = fmaxf(hp, __shfl_down(hp, 2)); hp = fmaxf(hp, __shfl_down(hp, 1));
    hn = fminf(hn, __shfl_down(hn, 2)); hn = fminf(hn, __shfl_down(hn, 1));
    ap = fmaxf(ap, __shfl_down(ap, 2)); ap = fmaxf(ap, __shfl_down(ap, 1));
    an = fmaxf(an, __shfl_down(an, 2)); an = fmaxf(an, __shfl_down(an, 1));
    __shared__ float sl[64], sc[64];
    if ((t & 3) == 0) {
        const int b = t >> 2;
        const float valid = (ap > 0.f && an > 0.f) ? 1.f : 0.f;
        sl[b] = fmaxf(hp - hn + MARGIN, 0.f) * valid;
        sc[b] = valid;
    }
    __syncthreads();
    if (t < 64) {
        float l = sl[t], c = sc[t];
        #pragma unroll
        for (int off = 32; off > 0; off >>= 1) {
            l += __shfl_down(l, off);
            c += __shfl_down(c, off);
        }
        if (t == 0) out[0] = (c > 0.f) ? (l / c) : 0.f;
    }
}

// ---------------------------------------------------------------------------
extern "C" void kernel_launch(void* const* d_in, const int* in_sizes, int n_in,
                              void* d_out, int out_size, void* d_ws, size_t ws_size,
                              hipStream_t stream) {
    const float* anchor = (const float*)d_in[0];   // (64, 512)
    const float* voxels = (const float*)d_in[1];   // (64, 32768)
    const float* keys   = (const float*)d_in[2];   // (2048, 512)
    const float* vals   = (const float*)d_in[3];   // (2048, 32768)

    float* ws = (float*)d_ws;
    float*  vsqp = ws + OFF_VSQP;
    float*  ainv = ws + OFF_AINV;
    float*  kinv = ws + OFF_KINV;
    float*  wsq  = ws + OFF_WSQ;
    float*  wsqp = ws + OFF_WSQP;
    float*  php  = ws + OFF_PHP;
    float*  phn  = ws + OFF_PHN;
    float*  pap  = ws + OFF_PAP;
    float*  pan  = ws + OFF_PAN;
    float*  keyp = ws + OFF_KEYP;
    float*  dotp = ws + OFF_DOTP;
    ushort* vhi  = (ushort*)(ws + OFF_VHI);
    ushort* vlo  = (ushort*)(ws + OFF_VLO);

    prep_kernel<<<784, 256, 0, stream>>>(voxels, anchor, keys, vhi, vlo, vsqp, ainv, kinv);
    gemm_big<<<32 * NS, 256, 0, stream>>>(vhi, vlo, vals, dotp, wsqp);
    keydist_kernel<<<264, 256, 0, stream>>>(anchor, keys, wsqp, keyp, wsq);
    rowpart_kernel<<<256, 256, 0, stream>>>(dotp, wsq, keyp, vsqp, ainv, kinv,
                                            php, phn, pap, pan);
    final_kernel<<<1, 256, 0, stream>>>(php, phn, pap, pan, (float*)d_out);
}